// Round 11
// baseline (68.182 us; speedup 1.0000x reference)
//
#include <hip/hip_runtime.h>
#include <math.h>

#define NS 1024
#define NU 32
#define ND 256
#define NROWS (NS * NU)             // 32768
#define NBM (NROWS / 128)           // 256 row-blocks
#define NBN (NS / 128)              // 8 col-blocks
#define NBLK2 (NBM * NBN)           // 2048 k2 blocks

static constexpr float EPS_POS = 1e-6f;
static constexpr float EPS_NEG = 1e-8f;

typedef __attribute__((ext_vector_type(8))) short bf16x8;
typedef __attribute__((ext_vector_type(4))) float f32x4;

#if __has_builtin(__builtin_amdgcn_exp2f)
#define EXP2F(x) __builtin_amdgcn_exp2f(x)
#else
#define EXP2F(x) exp2f(x)
#endif

static __device__ __forceinline__ unsigned short f2bf(float f) {
    union { float f; unsigned u; } v; v.f = f;
    unsigned r = v.u + 0x7fffu + ((v.u >> 16) & 1u);   // RNE
    return (unsigned short)(r >> 16);
}

// ---------------------------------------------------------------------------
// Kernel 1: per-speaker centroids (-> bf16 normalized cnb[t][d]), positive
// (LOO) cosines, and NORMALIZED bf16 ROWS dnb[r][d]. One block per speaker.
// ---------------------------------------------------------------------------
__global__ __launch_bounds__(256) void ge2e_k1(
    const float* __restrict__ dv, unsigned short* __restrict__ cnb,
    unsigned short* __restrict__ dnb, float* __restrict__ blk_pos)
{
    const int s = blockIdx.x;
    const int tid = threadIdx.x;
    const int wave = tid >> 6;
    const int lane = tid & 63;

    __shared__ float v[NU][ND];
    __shared__ float cs[ND];
    __shared__ float sinvs[NU];
    __shared__ float red[16];

    const float4* b4 = (const float4*)(dv + (size_t)s * (NU * ND));
    float4* v4 = (float4*)&v[0][0];
    #pragma unroll
    for (int it = 0; it < 8; ++it) v4[tid + it * 256] = b4[tid + it * 256];
    __syncthreads();

    {
        float a = 0.f;
        #pragma unroll
        for (int u = 0; u < NU; ++u) a += v[u][tid];
        cs[tid] = a;
    }
    __syncthreads();

    // centroid norm -> normalized centroid in bf16, row-major [t][d]
    float c = cs[tid] * (1.0f / NU);
    float p = c * c;
    #pragma unroll
    for (int off = 32; off > 0; off >>= 1) p += __shfl_xor(p, off, 64);
    if (lane == 0) red[wave] = p;
    __syncthreads();
    if (tid == 0) red[8] = red[0] + red[1] + red[2] + red[3];
    __syncthreads();
    {
        float rn = 1.0f / fmaxf(sqrtf(red[8]), EPS_NEG);
        cnb[(size_t)s * ND + tid] = f2bf(c * rn);
    }

    // per-utterance stats: wave w handles u = 8w .. 8w+7
    const float inv31 = 1.0f / (NU - 1);
    float pos_part = 0.f;
    const float4 cc = *(const float4*)&cs[lane * 4];
    for (int uu = 0; uu < 8; ++uu) {
        const int u = wave * 8 + uu;
        const float4 vv = *(const float4*)&v[u][lane * 4];
        float pv = 0.f, pp = 0.f, px = 0.f;
        float pc;
        pc = (cc.x - vv.x) * inv31; pv += vv.x * vv.x; pp += pc * pc; px += vv.x * pc;
        pc = (cc.y - vv.y) * inv31; pv += vv.y * vv.y; pp += pc * pc; px += vv.y * pc;
        pc = (cc.z - vv.z) * inv31; pv += vv.z * vv.z; pp += pc * pc; px += vv.z * pc;
        pc = (cc.w - vv.w) * inv31; pv += vv.w * vv.w; pp += pc * pc; px += vv.w * pc;
        #pragma unroll
        for (int off = 32; off > 0; off >>= 1) {
            pv += __shfl_xor(pv, off, 64);
            pp += __shfl_xor(pp, off, 64);
            px += __shfl_xor(px, off, 64);
        }
        if (lane == 0) {
            float nv = sqrtf(pv), npc = sqrtf(pp);
            pos_part += px / (fmaxf(nv, EPS_POS) * fmaxf(npc, EPS_POS));
            sinvs[u] = 1.0f / fmaxf(nv, EPS_NEG);
        }
    }
    if (lane == 0) red[4 + wave] = pos_part;
    __syncthreads();
    if (tid == 0) blk_pos[s] = red[4] + red[5] + red[6] + red[7];

    // normalized bf16 rows -> global (coalesced 16B stores)
    #pragma unroll
    for (int it = 0; it < 4; ++it) {
        const int idx = it * 2048 + tid * 8;
        const int u = idx >> 8, d0 = idx & 255;
        const float sc = sinvs[u];
        uint4 pk;
        pk.x = (unsigned)f2bf(v[u][d0 + 0] * sc) | ((unsigned)f2bf(v[u][d0 + 1] * sc) << 16);
        pk.y = (unsigned)f2bf(v[u][d0 + 2] * sc) | ((unsigned)f2bf(v[u][d0 + 3] * sc) << 16);
        pk.z = (unsigned)f2bf(v[u][d0 + 4] * sc) | ((unsigned)f2bf(v[u][d0 + 5] * sc) << 16);
        pk.w = (unsigned)f2bf(v[u][d0 + 6] * sc) | ((unsigned)f2bf(v[u][d0 + 7] * sc) << 16);
        *(uint4*)&dnb[(size_t)s * (NU * ND) + idx] = pk;
    }
}

// ---------------------------------------------------------------------------
// Kernel 2: m97-shape MFMA GEMM. Tile 128x128, K=256 in 4 steps of BK=64.
// Grid 2048 (256 bm x 8 bn), 256 threads = 4 waves (2 mw x 2 nw), each wave
// a 64x64 quadrant with acc[4][4] (f32x4). Per-wave state is SMALL (no A
// residency) -> ~160 VGPR, ~34 KB LDS -> ~3 blocks/CU, 12 waves/CU: m114's
// implicit wave-level overlap hides staging (the R3-R10 structures capped at
// 8 waves/CU and stalled). A,B staged per step via global_load_lds w=16 with
// involutive granule swizzle g^=(r&7) on source AND frag-read (rule 21).
// Epilogue ONCE per block: keep-masked exp2 fold, per-row partial sum-exp ->
// rowse[bn][row] (log deferred to k3 - cross-bn sum first), cos-sum ->
// blk_neg[blk]. All reduction orders fixed -> deterministic.
// ---------------------------------------------------------------------------
__global__ __launch_bounds__(256, 3) void ge2e_k2(
    const unsigned short* __restrict__ dnb, const unsigned short* __restrict__ cnb,
    const float* __restrict__ wp, float* __restrict__ rowse,
    float* __restrict__ blk_neg)
{
    const int blk = blockIdx.x;
    const int bm = blk >> 3;
    const int bn = blk & 7;
    const int tid = threadIdx.x;
    const int wv = tid >> 6;
    const int mw = wv >> 1;      // 0..1: rows mw*64..+64 of the 128-row tile
    const int nw = wv & 1;       // 0..1: cols nw*64..+64 of the 128-col tile
    const int l  = tid & 63;
    const int lr = l & 15;
    const int lg = l >> 4;

    __shared__ unsigned short As[128][64];   // 16 KB (row-major, swizzled granules)
    __shared__ unsigned short Bs[128][64];   // 16 KB (col t local x k)
    __shared__ float pse[2][128];
    __shared__ float psm[2][128];
    __shared__ float red2[2];

    const float w0 = wp[0];
    const float c2 = w0 * 1.4426950408889634f;   // w0 * log2(e)

    // --- staging sources: granule gi = i*256+tid (i<4: A, i>=4: B)
    // row r = gi>>3 (0..127), slot granule g = gi&7; source holds logical
    // granule g^(r&7) of (row r, K-step j)
    const char* dnbc = (const char*)dnb;
    const char* cnbc = (const char*)cnb;
    unsigned soA[4], soB[4];
    #pragma unroll
    for (int i = 0; i < 4; ++i) {
        const int gi = i * 256 + tid;
        const int r = gi >> 3, g = gi & 7;
        const unsigned sw = (unsigned)((g ^ (r & 7)) << 4);
        soA[i] = (unsigned)((bm * 128 + r) * 512) + sw;
        soB[i] = (unsigned)((bn * 128 + r) * 512) + sw;
    }

    f32x4 acc[4][4];
    #pragma unroll
    for (int mt = 0; mt < 4; ++mt)
        #pragma unroll
        for (int nt = 0; nt < 4; ++nt) acc[mt][nt] = (f32x4){0.f, 0.f, 0.f, 0.f};

    for (int j = 0; j < 4; ++j) {
        if (j) __syncthreads();            // all waves done reading step j-1
        const unsigned kb = (unsigned)j * 128;   // K-step byte offset in row
        #pragma unroll
        for (int i = 0; i < 4; ++i) {
            __builtin_amdgcn_global_load_lds(
                (const __attribute__((address_space(1))) void*)(dnbc + soA[i] + kb),
                (__attribute__((address_space(3))) void*)((char*)&As[0][0] + (i * 256 + wv * 64) * 16),
                16, 0, 0);
            __builtin_amdgcn_global_load_lds(
                (const __attribute__((address_space(1))) void*)(cnbc + soB[i] + kb),
                (__attribute__((address_space(3))) void*)((char*)&Bs[0][0] + (i * 256 + wv * 64) * 16),
                16, 0, 0);
        }
        __syncthreads();                   // drains vmcnt(0): stage j landed

        #pragma unroll
        for (int kt = 0; kt < 2; ++kt) {
            bf16x8 af[4], bf[4];
            #pragma unroll
            for (int mt = 0; mt < 4; ++mt) {
                const int r = mw * 64 + mt * 16 + lr;
                const int g = (kt * 4 + lg) ^ (r & 7);
                af[mt] = *(const bf16x8*)((const char*)&As[0][0] + r * 128 + (g << 4));
            }
            #pragma unroll
            for (int nt = 0; nt < 4; ++nt) {
                const int r = nw * 64 + nt * 16 + lr;
                const int g = (kt * 4 + lg) ^ (r & 7);
                bf[nt] = *(const bf16x8*)((const char*)&Bs[0][0] + r * 128 + (g << 4));
            }
            #pragma unroll
            for (int mt = 0; mt < 4; ++mt)
                #pragma unroll
                for (int nt = 0; nt < 4; ++nt)
                    acc[mt][nt] = __builtin_amdgcn_mfma_f32_16x16x32_bf16(af[mt], bf[nt], acc[mt][nt], 0, 0, 0);
        }
    }

    // --- epilogue (once per block): keep-masked exp2 fold
    // C/D: row_in_subtile = lg*4+r, col_in_subtile = lr
    float sef[4][4], smf[4][4];   // [mt][r]
    #pragma unroll
    for (int mt = 0; mt < 4; ++mt)
        #pragma unroll
        for (int r = 0; r < 4; ++r) { sef[mt][r] = 0.f; smf[mt][r] = 0.f; }

    #pragma unroll
    for (int mt = 0; mt < 4; ++mt) {
        const int sp = bm * 4 + mw * 2 + (mt >> 1);   // speaker of these 16 rows
        const bool inw = ((sp >> 6) == bn * 2 + nw);
        const int nto = (sp >> 4) & 3;
        const int spl = sp & 15;
        #pragma unroll
        for (int nt = 0; nt < 4; ++nt) {
            const float keep = (inw && nt == nto && lr == spl) ? 0.f : 1.f;
            #pragma unroll
            for (int r = 0; r < 4; ++r) {
                const float cv = acc[mt][nt][r];
                sef[mt][r] += keep * EXP2F(fmaf(c2, cv, -c2));
                smf[mt][r] += keep * cv;
            }
        }
    }

    // reduce over the 16 column-lanes (xor bits 0..3)
    #pragma unroll
    for (int mask = 1; mask <= 8; mask <<= 1)
        #pragma unroll
        for (int mt = 0; mt < 4; ++mt)
            #pragma unroll
            for (int r = 0; r < 4; ++r) {
                sef[mt][r] += __shfl_xor(sef[mt][r], mask, 64);
                smf[mt][r] += __shfl_xor(smf[mt][r], mask, 64);
            }

    if (lr == 0) {
        #pragma unroll
        for (int mt = 0; mt < 4; ++mt)
            #pragma unroll
            for (int r = 0; r < 4; ++r) {
                const int row = mw * 64 + mt * 16 + lg * 4 + r;
                pse[nw][row] = sef[mt][r];
                psm[nw][row] = smf[mt][r];
            }
    }
    __syncthreads();

    if (tid < 128) {
        const float st = pse[0][tid] + pse[1][tid];
        float sm = psm[0][tid] + psm[1][tid];
        rowse[(size_t)bn * NROWS + bm * 128 + tid] = st;
        #pragma unroll
        for (int mask = 1; mask <= 32; mask <<= 1)
            sm += __shfl_xor(sm, mask, 64);
        if ((tid & 63) == 0) red2[tid >> 6] = sm;
    }
    __syncthreads();
    if (tid == 0) blk_neg[blk] = red2[0] + red2[1];
}

// ---------------------------------------------------------------------------
// Kernel 3: per-row lse over the 8 combined column partials + final
// reduction -> (loss, pos_mean, neg_mean). One block x 1024 threads.
// ---------------------------------------------------------------------------
__global__ __launch_bounds__(1024) void ge2e_k3(
    const float* __restrict__ blk_pos, const float* __restrict__ blk_neg,
    const float* __restrict__ rowse, const float* __restrict__ wp,
    const float* __restrict__ bp, float* __restrict__ out)
{
    const int tid = threadIdx.x;
    __shared__ float red[48];

    float p = 0.f, n = 0.f, l = 0.f;
    if (tid < NS) p = blk_pos[tid];
    for (int i = tid; i < NBLK2; i += 1024) n += blk_neg[i];
    for (int r = tid; r < NROWS; r += 1024) {
        float st = 0.f;
        #pragma unroll
        for (int q = 0; q < NBN; ++q) st += rowse[(size_t)q * NROWS + r];
        l += __logf(st);
    }

    #pragma unroll
    for (int off = 32; off > 0; off >>= 1) {
        p += __shfl_xor(p, off, 64);
        n += __shfl_xor(n, off, 64);
        l += __shfl_xor(l, off, 64);
    }
    const int wave = tid >> 6, lane = tid & 63;
    if (lane == 0) { red[wave] = p; red[16 + wave] = n; red[32 + wave] = l; }
    __syncthreads();
    if (tid == 0) {
        float ps = 0.f, ns = 0.f, ls = 0.f;
        #pragma unroll
        for (int q = 0; q < 16; ++q) {
            ps += red[q]; ns += red[16 + q]; ls += red[32 + q];
        }
        const float w0 = wp[0];
        const float b0 = bp[0];
        const float pos_mean = ps * (1.0f / NROWS);
        const float neg_mean = ns / ((float)NS * (float)NU * (float)(NS - 1));
        const float lse_mean = w0 + b0 + ls * (1.0f / NROWS);
        const float loss = -(w0 * pos_mean + b0) + lse_mean;
        out[0] = loss;
        out[1] = pos_mean;
        out[2] = neg_mean;
    }
}

extern "C" void kernel_launch(void* const* d_in, const int* in_sizes, int n_in,
                              void* d_out, int out_size, void* d_ws, size_t ws_size,
                              hipStream_t stream)
{
    const float* dv = (const float*)d_in[0];
    const float* w  = (const float*)d_in[1];
    const float* b  = (const float*)d_in[2];
    float* out = (float*)d_out;

    unsigned short* cnb = (unsigned short*)d_ws;           // [NS][ND] bf16, 512 KB
    unsigned short* dnb = cnb + (size_t)NS * ND;           // [NROWS][ND] bf16, 16.8 MB
    float* blk_pos = (float*)(dnb + (size_t)NROWS * ND);   // [NS]
    float* blk_neg = blk_pos + NS;                         // [NBLK2]
    float* rowse   = blk_neg + NBLK2;                      // [NBN * NROWS] = 1 MB

    hipLaunchKernelGGL(ge2e_k1, dim3(NS), dim3(256), 0, stream,
                       dv, cnb, dnb, blk_pos);
    hipLaunchKernelGGL(ge2e_k2, dim3(NBLK2), dim3(256), 0, stream,
                       dnb, cnb, w, rowse, blk_neg);
    hipLaunchKernelGGL(ge2e_k3, dim3(1), dim3(1024), 0, stream,
                       blk_pos, blk_neg, rowse, w, b, out);
}